// Round 1
// baseline (627.405 us; speedup 1.0000x reference)
//
#include <hip/hip_runtime.h>
#include <stdint.h>

#define SEQ 2048
#define NBATCH 4
#define MROWS (NBATCH*SEQ)   // 8192

typedef __attribute__((ext_vector_type(8))) short short8;
typedef __attribute__((ext_vector_type(8))) unsigned short ushort8;
typedef __attribute__((ext_vector_type(4))) unsigned short ushort4_t;
typedef __attribute__((ext_vector_type(4))) float f32x4;

__device__ __forceinline__ unsigned short f32_to_bf16(float f) {
  union { float f; unsigned int u; } v; v.f = f;
  unsigned int r = v.u + 0x7fffu + ((v.u >> 16) & 1u);
  return (unsigned short)(r >> 16);
}
__device__ __forceinline__ float bf16_to_f32(unsigned short h) {
  union { float f; unsigned int u; } v; v.u = ((unsigned int)h) << 16;
  return v.f;
}

// ---------------- GEMM: C[M][1024] = A[M][1024] @ W[1024][1024]^T + bias ----
// SPLIT: hi/lo bf16 decomposition of A and B, 3 MFMAs/step (near-fp32)
// ABF16: A is bf16 (single plane) instead of f32
// EPI: 0 = split bf16 store (outH,outL); 1 = per-head transposed bf16 (Vt);
//      2 = f32 store (outF)
template<int SPLIT, int ABF16, int EPI>
__global__ __launch_bounds__(256) void gemm_k(
    const void* __restrict__ Aptr, const float* __restrict__ B,
    const float* __restrict__ bias,
    unsigned short* __restrict__ outH, unsigned short* __restrict__ outL,
    float* __restrict__ outF)
{
  __shared__ unsigned short Ah[128*32];
  __shared__ unsigned short Bh[128*32];
  __shared__ unsigned short Al[SPLIT ? 128*32 : 8];
  __shared__ unsigned short Bl[SPLIT ? 128*32 : 8];

  const int tid  = threadIdx.x;
  const int lane = tid & 63;
  const int w    = tid >> 6;
  const int wm   = w >> 1, wn = w & 1;
  const int row0 = blockIdx.x * 128;
  const int col0 = blockIdx.y * 128;

  f32x4 acc[4][4] = {};

  for (int k0 = 0; k0 < 1024; k0 += 32) {
    __syncthreads();
    // ---- stage A,B tiles (convert f32 -> bf16 hi/lo on the fly) ----
    #pragma unroll
    for (int i = 0; i < 2; ++i) {
      int c = tid + i*256;            // 0..511 chunks of 8 elements
      int r = c >> 2, slot = c & 3;   // 128 rows x 4 slots
      int sslot = slot ^ ((r >> 1) & 3);   // 2-way-max bank swizzle
      int lidx = r*32 + sslot*8;
      if (ABF16) {
        ushort8 av = *(const ushort8*)((const unsigned short*)Aptr + (size_t)(row0 + r)*1024 + k0 + slot*8);
        *(ushort8*)&Ah[lidx] = av;
      } else {
        const float* ap = (const float*)Aptr + (size_t)(row0 + r)*1024 + k0 + slot*8;
        float4 f0 = *(const float4*)ap;
        float4 f1 = *(const float4*)(ap + 4);
        float fs[8] = {f0.x,f0.y,f0.z,f0.w,f1.x,f1.y,f1.z,f1.w};
        ushort8 hv, lv;
        #pragma unroll
        for (int j=0;j<8;++j) {
          unsigned short hb = f32_to_bf16(fs[j]);
          hv[j] = hb;
          if (SPLIT) lv[j] = f32_to_bf16(fs[j] - bf16_to_f32(hb));
        }
        *(ushort8*)&Ah[lidx] = hv;
        if (SPLIT) *(ushort8*)&Al[lidx] = lv;
      }
      {
        const float* bp = B + (size_t)(col0 + r)*1024 + k0 + slot*8;
        float4 f0 = *(const float4*)bp;
        float4 f1 = *(const float4*)(bp + 4);
        float fs[8] = {f0.x,f0.y,f0.z,f0.w,f1.x,f1.y,f1.z,f1.w};
        ushort8 hv, lv;
        #pragma unroll
        for (int j=0;j<8;++j) {
          unsigned short hb = f32_to_bf16(fs[j]);
          hv[j] = hb;
          if (SPLIT) lv[j] = f32_to_bf16(fs[j] - bf16_to_f32(hb));
        }
        *(ushort8*)&Bh[lidx] = hv;
        if (SPLIT) *(ushort8*)&Bl[lidx] = lv;
      }
    }
    __syncthreads();

    // ---- MFMA: each wave does 64x64 = 4x4 fragments ----
    short8 a_h[4], a_l[4], b_h[4], b_l[4];
    const int slotR = lane >> 4;
    #pragma unroll
    for (int m=0;m<4;++m) {
      int r = wm*64 + m*16 + (lane & 15);
      int idx = r*32 + ((slotR ^ ((r>>1)&3))*8);
      a_h[m] = *(const short8*)&Ah[idx];
      if (SPLIT) a_l[m] = *(const short8*)&Al[idx];
    }
    #pragma unroll
    for (int nn=0;nn<4;++nn) {
      int r = wn*64 + nn*16 + (lane & 15);
      int idx = r*32 + ((slotR ^ ((r>>1)&3))*8);
      b_h[nn] = *(const short8*)&Bh[idx];
      if (SPLIT) b_l[nn] = *(const short8*)&Bl[idx];
    }
    #pragma unroll
    for (int m=0;m<4;++m)
      #pragma unroll
      for (int nn=0;nn<4;++nn) {
        acc[m][nn] = __builtin_amdgcn_mfma_f32_16x16x32_bf16(a_h[m], b_h[nn], acc[m][nn],0,0,0);
        if (SPLIT) {
          acc[m][nn] = __builtin_amdgcn_mfma_f32_16x16x32_bf16(a_h[m], b_l[nn], acc[m][nn],0,0,0);
          acc[m][nn] = __builtin_amdgcn_mfma_f32_16x16x32_bf16(a_l[m], b_h[nn], acc[m][nn],0,0,0);
        }
      }
  }

  // ---- epilogue (C frag: col=lane&15, row=(lane>>4)*4+r) ----
  #pragma unroll
  for (int m=0;m<4;++m) {
    #pragma unroll
    for (int nn=0;nn<4;++nn) {
      int gcol = col0 + wn*64 + nn*16 + (lane & 15);
      float bsv = bias[gcol];
      if (EPI == 1) {
        int rbase = row0 + wm*64 + m*16 + (lane>>4)*4;
        int nIdx = rbase >> 11, s0 = rbase & 2047;
        ushort4_t pk;
        #pragma unroll
        for (int r2=0;r2<4;++r2) pk[r2] = f32_to_bf16(acc[m][nn][r2] + bsv);
        *(ushort4_t*)&outH[((size_t)(nIdx*1024 + gcol))*2048 + s0] = pk;
      } else {
        #pragma unroll
        for (int r2=0;r2<4;++r2) {
          int grow = row0 + wm*64 + m*16 + (lane>>4)*4 + r2;
          float v = acc[m][nn][r2] + bsv;
          if (EPI == 0) {
            unsigned short hb = f32_to_bf16(v);
            outH[(size_t)grow*1024 + gcol] = hb;
            outL[(size_t)grow*1024 + gcol] = f32_to_bf16(v - bf16_to_f32(hb));
          } else {
            outF[(size_t)grow*1024 + gcol] = v;
          }
        }
      }
    }
  }
}

// ---------------- Flash attention (no 1/sqrt(d) scaling!) ----------------
// grid (32 qtiles, 64 n*h); 4 waves x 16 q-rows. K hi/lo in LDS (split QK^T),
// online softmax in registers, P via per-wave LDS, V from global Vt[d][s].
__global__ __launch_bounds__(256) void attn_k(
  const unsigned short* __restrict__ Qh, const unsigned short* __restrict__ Ql,
  const unsigned short* __restrict__ Kh, const unsigned short* __restrict__ Kl,
  const unsigned short* __restrict__ Vt, unsigned short* __restrict__ AO)
{
  __shared__ unsigned short Ks [64*64];
  __shared__ unsigned short Kls[64*64];
  __shared__ unsigned short Ps [4*16*64];

  const int tid = threadIdx.x, lane = tid & 63, w = tid >> 6;
  const int qt = blockIdx.x, nh = blockIdx.y;
  const int n = nh >> 4, h = nh & 15;

  // Q fragments in registers (hi+lo, 2 k-steps of 32 over head_dim 64)
  short8 qhf[2], qlf[2];
  {
    int qrow = n*SEQ + qt*64 + w*16 + (lane & 15);
    #pragma unroll
    for (int ks=0; ks<2; ++ks) {
      size_t off = (size_t)qrow*1024 + h*64 + ks*32 + (lane>>4)*8;
      qhf[ks] = *(const short8*)&Qh[off];
      qlf[ks] = *(const short8*)&Ql[off];
    }
  }

  f32x4 o[4] = {};
  float mrun[4], lrun[4];
  #pragma unroll
  for (int r=0;r<4;++r){ mrun[r] = -1e30f; lrun[r] = 0.f; }

  for (int kt = 0; kt < 32; ++kt) {
    __syncthreads();
    // stage K tile hi+lo (64 rows x 64 dims), 8-slot XOR swizzle
    #pragma unroll
    for (int i=0;i<2;++i) {
      int c = tid + i*256;          // 0..511
      int r = c >> 3, slot = c & 7;
      size_t goff = (size_t)(n*SEQ + kt*64 + r)*1024 + h*64 + slot*8;
      int lidx = r*64 + ((slot ^ (r & 7))*8);
      *(ushort8*)&Ks [lidx] = *(const ushort8*)&Kh[goff];
      *(ushort8*)&Kls[lidx] = *(const ushort8*)&Kl[goff];
    }
    __syncthreads();

    // S = Q K^T  (split: qh*kh + ql*kh + qh*kl)
    f32x4 s[4] = {};
    #pragma unroll
    for (int nf=0; nf<4; ++nf) {
      #pragma unroll
      for (int ks=0; ks<2; ++ks) {
        int r = nf*16 + (lane & 15);
        int slot = ks*4 + (lane>>4);
        int lidx = r*64 + ((slot ^ (r & 7))*8);
        short8 kb  = *(const short8*)&Ks [lidx];
        short8 kl2 = *(const short8*)&Kls[lidx];
        s[nf] = __builtin_amdgcn_mfma_f32_16x16x32_bf16(qhf[ks], kb,  s[nf],0,0,0);
        s[nf] = __builtin_amdgcn_mfma_f32_16x16x32_bf16(qlf[ks], kb,  s[nf],0,0,0);
        s[nf] = __builtin_amdgcn_mfma_f32_16x16x32_bf16(qhf[ks], kl2, s[nf],0,0,0);
      }
    }

    // online softmax (rows live in 16-lane groups; butterfly reduce)
    float pv[4][4];
    #pragma unroll
    for (int r=0;r<4;++r) {
      float tm = fmaxf(fmaxf(s[0][r], s[1][r]), fmaxf(s[2][r], s[3][r]));
      #pragma unroll
      for (int msk=1; msk<16; msk<<=1) tm = fmaxf(tm, __shfl_xor(tm, msk, 64));
      float mn = fmaxf(mrun[r], tm);
      float scale = __expf(mrun[r] - mn);
      float rs = 0.f;
      #pragma unroll
      for (int nf=0; nf<4; ++nf) { float p = __expf(s[nf][r] - mn); pv[nf][r] = p; rs += p; }
      #pragma unroll
      for (int msk=1; msk<16; msk<<=1) rs += __shfl_xor(rs, msk, 64);
      lrun[r] = lrun[r]*scale + rs;
      mrun[r] = mn;
      #pragma unroll
      for (int df=0; df<4; ++df) o[df][r] *= scale;
    }

    // P -> per-wave LDS (swizzled rows of 64 bf16)
    #pragma unroll
    for (int nf=0; nf<4; ++nf)
      #pragma unroll
      for (int r=0;r<4;++r) {
        int prow = (lane>>4)*4 + r;
        int c = nf*16 + (lane & 15);
        int slot = c >> 3;
        Ps[w*1024 + prow*64 + ((slot ^ (prow & 7))*8) + (c & 7)] = f32_to_bf16(pv[nf][r]);
      }
    __syncthreads();

    // O += P @ V  (V from transposed per-head layout, B^T-style fragments)
    #pragma unroll
    for (int ks2=0; ks2<2; ++ks2) {
      int prow = lane & 15;
      int slot = ks2*4 + (lane>>4);
      short8 pa = *(const short8*)&Ps[w*1024 + prow*64 + ((slot ^ (prow & 7))*8)];
      #pragma unroll
      for (int df=0; df<4; ++df) {
        size_t voff = ((size_t)(n*1024 + h*64 + df*16 + (lane & 15)))*SEQ + kt*64 + ks2*32 + (lane>>4)*8;
        short8 vb = *(const short8*)&Vt[voff];
        o[df] = __builtin_amdgcn_mfma_f32_16x16x32_bf16(pa, vb, o[df],0,0,0);
      }
    }
  }

  // write attention output (bf16) back in [row][h*64+d] layout
  #pragma unroll
  for (int df=0; df<4; ++df)
    #pragma unroll
    for (int r=0;r<4;++r) {
      int prow = (lane>>4)*4 + r;
      int qrow = n*SEQ + qt*64 + w*16 + prow;
      int col  = h*64 + df*16 + (lane & 15);
      AO[(size_t)qrow*1024 + col] = f32_to_bf16(o[df][r] / lrun[r]);
    }
}

extern "C" void kernel_launch(void* const* d_in, const int* in_sizes, int n_in,
                              void* d_out, int out_size, void* d_ws, size_t ws_size,
                              hipStream_t stream)
{
  (void)in_sizes; (void)n_in; (void)out_size; (void)ws_size;
  const float* query = (const float*)d_in[0];
  const float* key   = (const float*)d_in[1];
  const float* value = (const float*)d_in[2];
  const float* Wq = (const float*)d_in[3];
  const float* bq = (const float*)d_in[4];
  const float* Wk = (const float*)d_in[5];
  const float* bk = (const float*)d_in[6];
  const float* Wv = (const float*)d_in[7];
  const float* bv = (const float*)d_in[8];
  const float* Wo = (const float*)d_in[9];
  const float* bo = (const float*)d_in[10];
  float* out = (float*)d_out;

  unsigned short* ws = (unsigned short*)d_ws;
  const size_t PLANE = (size_t)MROWS * 1024;
  unsigned short* Qh = ws;
  unsigned short* Ql = Qh + PLANE;
  unsigned short* Kh = Ql + PLANE;
  unsigned short* Kl = Kh + PLANE;
  unsigned short* Vt = Kl + PLANE;   // [ (n*16+h)*64+d ][ s ]
  unsigned short* AO = Vt + PLANE;

  dim3 gg(64, 8), bb(256);
  gemm_k<1,0,0><<<gg, bb, 0, stream>>>(query, Wq, bq, Qh, Ql, nullptr);
  gemm_k<1,0,0><<<gg, bb, 0, stream>>>(key,   Wk, bk, Kh, Kl, nullptr);
  gemm_k<0,0,1><<<gg, bb, 0, stream>>>(value, Wv, bv, Vt, nullptr, nullptr);
  attn_k<<<dim3(32,64), bb, 0, stream>>>(Qh, Ql, Kh, Kl, Vt, AO);
  gemm_k<0,1,2><<<gg, bb, 0, stream>>>(AO, Wo, bo, nullptr, nullptr, out);
}

// Round 2
// 535.427 us; speedup vs baseline: 1.1718x; 1.1718x over previous
//
#include <hip/hip_runtime.h>
#include <stdint.h>

#define SEQ 2048
#define MROWS 8192

typedef __attribute__((ext_vector_type(8))) _Float16 f16x8;
typedef __attribute__((ext_vector_type(8))) unsigned short ushort8;
typedef __attribute__((ext_vector_type(4))) unsigned short ushort4_t;
typedef __attribute__((ext_vector_type(4))) float f32x4;

__device__ __forceinline__ unsigned short f32_to_f16u(float f) {
  union { _Float16 h; unsigned short u; } v; v.h = (_Float16)f; return v.u;
}

// ---------------- fused QKV projection GEMM ----------------
// z=0: Q -> f16 plane; z=1: K -> f16 plane; z=2: V -> per-head transposed f16
// C[M][1024] = A[M][1024] @ W[1024][1024]^T + b
__global__ __launch_bounds__(256) void qkv_k(
    const float* __restrict__ Aq, const float* __restrict__ Ak, const float* __restrict__ Av,
    const float* __restrict__ Wq, const float* __restrict__ Wk, const float* __restrict__ Wv,
    const float* __restrict__ bq, const float* __restrict__ bk, const float* __restrict__ bv,
    unsigned short* __restrict__ Qf, unsigned short* __restrict__ Kf, unsigned short* __restrict__ Vt)
{
  const int z = blockIdx.z;
  const float* __restrict__ A    = (z==0)? Aq : (z==1)? Ak : Av;
  const float* __restrict__ W    = (z==0)? Wq : (z==1)? Wk : Wv;
  const float* __restrict__ bias = (z==0)? bq : (z==1)? bk : bv;

  __shared__ unsigned short Ah[128*32];
  __shared__ unsigned short Bh[128*32];

  const int tid  = threadIdx.x;
  const int lane = tid & 63;
  const int w    = tid >> 6;
  const int wm   = w >> 1, wn = w & 1;
  const int row0 = blockIdx.x * 128;
  const int col0 = blockIdx.y * 128;

  f32x4 acc[4][4] = {};

  for (int k0 = 0; k0 < 1024; k0 += 32) {
    __syncthreads();
    #pragma unroll
    for (int i = 0; i < 2; ++i) {
      int c = tid + i*256;            // 0..511 chunks of 8 elements
      int r = c >> 2, slot = c & 3;   // 128 rows x 4 slots
      int lidx = r*32 + ((slot ^ ((r >> 1) & 3))*8);
      {
        const float* ap = A + (size_t)(row0 + r)*1024 + k0 + slot*8;
        float4 f0 = *(const float4*)ap;
        float4 f1 = *(const float4*)(ap + 4);
        float fs[8] = {f0.x,f0.y,f0.z,f0.w,f1.x,f1.y,f1.z,f1.w};
        ushort8 hv;
        #pragma unroll
        for (int j=0;j<8;++j) hv[j] = f32_to_f16u(fs[j]);
        *(ushort8*)&Ah[lidx] = hv;
      }
      {
        const float* bp = W + (size_t)(col0 + r)*1024 + k0 + slot*8;
        float4 f0 = *(const float4*)bp;
        float4 f1 = *(const float4*)(bp + 4);
        float fs[8] = {f0.x,f0.y,f0.z,f0.w,f1.x,f1.y,f1.z,f1.w};
        ushort8 hv;
        #pragma unroll
        for (int j=0;j<8;++j) hv[j] = f32_to_f16u(fs[j]);
        *(ushort8*)&Bh[lidx] = hv;
      }
    }
    __syncthreads();

    f16x8 a_[4], b_[4];
    const int slotR = lane >> 4;
    #pragma unroll
    for (int m=0;m<4;++m) {
      int r = wm*64 + m*16 + (lane & 15);
      a_[m] = *(const f16x8*)&Ah[r*32 + ((slotR ^ ((r>>1)&3))*8)];
    }
    #pragma unroll
    for (int nn=0;nn<4;++nn) {
      int r = wn*64 + nn*16 + (lane & 15);
      b_[nn] = *(const f16x8*)&Bh[r*32 + ((slotR ^ ((r>>1)&3))*8)];
    }
    #pragma unroll
    for (int m=0;m<4;++m)
      #pragma unroll
      for (int nn=0;nn<4;++nn)
        acc[m][nn] = __builtin_amdgcn_mfma_f32_16x16x32_f16(a_[m], b_[nn], acc[m][nn],0,0,0);
  }

  // epilogue (C frag: col=lane&15, row=(lane>>4)*4+r)
  #pragma unroll
  for (int m=0;m<4;++m) {
    #pragma unroll
    for (int nn=0;nn<4;++nn) {
      int gcol = col0 + wn*64 + nn*16 + (lane & 15);
      float bsv = bias[gcol];
      if (z == 2) {
        int rbase = row0 + wm*64 + m*16 + (lane>>4)*4;
        int nIdx = rbase >> 11, s0 = rbase & 2047;
        ushort4_t pk;
        #pragma unroll
        for (int r2=0;r2<4;++r2) pk[r2] = f32_to_f16u(acc[m][nn][r2] + bsv);
        *(ushort4_t*)&Vt[((size_t)(nIdx*1024 + gcol))*2048 + s0] = pk;
      } else {
        unsigned short* __restrict__ dst = (z==0)? Qf : Kf;
        #pragma unroll
        for (int r2=0;r2<4;++r2) {
          int grow = row0 + wm*64 + m*16 + (lane>>4)*4 + r2;
          dst[(size_t)grow*1024 + gcol] = f32_to_f16u(acc[m][nn][r2] + bsv);
        }
      }
    }
  }
}

// ---------------- output projection: out = AO(f16) @ Wo^T + bo (f32) -------
__global__ __launch_bounds__(256) void oproj_k(
    const unsigned short* __restrict__ AO, const float* __restrict__ W,
    const float* __restrict__ bias, float* __restrict__ out)
{
  __shared__ unsigned short Ah[128*32];
  __shared__ unsigned short Bh[128*32];

  const int tid  = threadIdx.x;
  const int lane = tid & 63;
  const int w    = tid >> 6;
  const int wm   = w >> 1, wn = w & 1;
  const int row0 = blockIdx.x * 128;
  const int col0 = blockIdx.y * 128;

  f32x4 acc[4][4] = {};

  for (int k0 = 0; k0 < 1024; k0 += 32) {
    __syncthreads();
    #pragma unroll
    for (int i = 0; i < 2; ++i) {
      int c = tid + i*256;
      int r = c >> 2, slot = c & 3;
      int lidx = r*32 + ((slot ^ ((r >> 1) & 3))*8);
      *(ushort8*)&Ah[lidx] = *(const ushort8*)&AO[(size_t)(row0 + r)*1024 + k0 + slot*8];
      {
        const float* bp = W + (size_t)(col0 + r)*1024 + k0 + slot*8;
        float4 f0 = *(const float4*)bp;
        float4 f1 = *(const float4*)(bp + 4);
        float fs[8] = {f0.x,f0.y,f0.z,f0.w,f1.x,f1.y,f1.z,f1.w};
        ushort8 hv;
        #pragma unroll
        for (int j=0;j<8;++j) hv[j] = f32_to_f16u(fs[j]);
        *(ushort8*)&Bh[lidx] = hv;
      }
    }
    __syncthreads();

    f16x8 a_[4], b_[4];
    const int slotR = lane >> 4;
    #pragma unroll
    for (int m=0;m<4;++m) {
      int r = wm*64 + m*16 + (lane & 15);
      a_[m] = *(const f16x8*)&Ah[r*32 + ((slotR ^ ((r>>1)&3))*8)];
    }
    #pragma unroll
    for (int nn=0;nn<4;++nn) {
      int r = wn*64 + nn*16 + (lane & 15);
      b_[nn] = *(const f16x8*)&Bh[r*32 + ((slotR ^ ((r>>1)&3))*8)];
    }
    #pragma unroll
    for (int m=0;m<4;++m)
      #pragma unroll
      for (int nn=0;nn<4;++nn)
        acc[m][nn] = __builtin_amdgcn_mfma_f32_16x16x32_f16(a_[m], b_[nn], acc[m][nn],0,0,0);
  }

  #pragma unroll
  for (int m=0;m<4;++m)
    #pragma unroll
    for (int nn=0;nn<4;++nn) {
      int gcol = col0 + wn*64 + nn*16 + (lane & 15);
      float bsv = bias[gcol];
      #pragma unroll
      for (int r2=0;r2<4;++r2) {
        int grow = row0 + wm*64 + m*16 + (lane>>4)*4 + r2;
        out[(size_t)grow*1024 + gcol] = acc[m][nn][r2] + bsv;
      }
    }
}

// ---------------- Flash attention (f16, KVBLK=128, K double-buffered) ------
// grid (32 qtiles, 64 n*h); 4 waves x 16 q-rows; 1 barrier per KV iteration.
__global__ __launch_bounds__(256) void attn_k(
  const unsigned short* __restrict__ Qf, const unsigned short* __restrict__ Kf,
  const unsigned short* __restrict__ Vt, unsigned short* __restrict__ AO)
{
  __shared__ unsigned short Ks[2][128*64];  // double-buffered K tile (swizzled)
  __shared__ unsigned short Ps[4*2048];     // per-wave P (16 x 128, swizzled)

  const int tid = threadIdx.x, lane = tid & 63, w = tid >> 6;
  const int qt = blockIdx.x, nh = blockIdx.y;
  const int n = nh >> 4, h = nh & 15;

  // Q fragments in registers (2 k-steps of 32 over head_dim 64)
  f16x8 qf[2];
  {
    int qrow = n*SEQ + qt*64 + w*16 + (lane & 15);
    #pragma unroll
    for (int ks=0; ks<2; ++ks)
      qf[ks] = *(const f16x8*)&Qf[(size_t)qrow*1024 + h*64 + ks*32 + (lane>>4)*8];
  }

  f32x4 o[4] = {};
  float mrun[4], lrun[4];
  #pragma unroll
  for (int r=0;r<4;++r){ mrun[r] = -1e30f; lrun[r] = 0.f; }

  const size_t kbase = (size_t)(n*SEQ)*1024 + h*64;
  const size_t vbase = ((size_t)(n*1024 + h*64))*SEQ;

  // prologue: stage tile 0
  ushort8 kreg[4];
  #pragma unroll
  for (int i=0;i<4;++i){
    int c = tid + i*256; int r = c>>3, sl = c&7;
    kreg[i] = *(const ushort8*)&Kf[kbase + (size_t)r*1024 + sl*8];
  }
  #pragma unroll
  for (int i=0;i<4;++i){
    int c = tid + i*256; int r = c>>3, sl = c&7;
    *(ushort8*)&Ks[0][r*64 + ((sl^(r&7))*8)] = kreg[i];
  }
  __syncthreads();

  int cur = 0;
  for (int kt = 0; kt < 16; ++kt) {
    // issue next K tile loads (hide HBM/L2 latency under compute)
    if (kt < 15) {
      #pragma unroll
      for (int i=0;i<4;++i){
        int c = tid + i*256; int r = c>>3, sl = c&7;
        kreg[i] = *(const ushort8*)&Kf[kbase + (size_t)((kt+1)*128 + r)*1024 + sl*8];
      }
    }

    // S = Q K^T  (rows: q-rows of this wave; cols: 128 k-rows)
    f32x4 s[8];
    #pragma unroll
    for (int nf=0; nf<8; ++nf) s[nf] = f32x4{0.f,0.f,0.f,0.f};
    #pragma unroll
    for (int nf=0; nf<8; ++nf) {
      int rr = nf*16 + (lane & 15);
      #pragma unroll
      for (int ks=0; ks<2; ++ks) {
        int sl = ks*4 + (lane>>4);
        f16x8 kb = *(const f16x8*)&Ks[cur][rr*64 + ((sl^(rr&7))*8)];
        s[nf] = __builtin_amdgcn_mfma_f32_16x16x32_f16(qf[ks], kb, s[nf],0,0,0);
      }
    }

    // online softmax (rows in 16-lane groups) + P store (fused)
    #pragma unroll
    for (int r=0;r<4;++r) {
      float tm = s[0][r];
      #pragma unroll
      for (int nf=1; nf<8; ++nf) tm = fmaxf(tm, s[nf][r]);
      #pragma unroll
      for (int msk=1; msk<16; msk<<=1) tm = fmaxf(tm, __shfl_xor(tm, msk, 64));
      float mn = fmaxf(mrun[r], tm);
      float sc = __expf(mrun[r] - mn);
      int prow = (lane>>4)*4 + r;
      float rs = 0.f;
      #pragma unroll
      for (int nf=0; nf<8; ++nf) {
        float p = __expf(s[nf][r] - mn);
        rs += p;
        int c2 = nf*16 + (lane & 15);
        Ps[w*2048 + prow*128 + (((c2>>3) ^ (prow&7))*8) + (c2&7)] = f32_to_f16u(p);
      }
      #pragma unroll
      for (int msk=1; msk<16; msk<<=1) rs += __shfl_xor(rs, msk, 64);
      lrun[r] = lrun[r]*sc + rs;
      mrun[r] = mn;
      #pragma unroll
      for (int df=0; df<4; ++df) o[df][r] *= sc;
    }

    // O += P @ V  (V from per-head transposed layout, L2-resident)
    #pragma unroll
    for (int ks2=0; ks2<4; ++ks2) {
      int prow = lane & 15;
      f16x8 pa = *(const f16x8*)&Ps[w*2048 + prow*128 + ((((ks2*4)+(lane>>4)) ^ (prow&7))*8)];
      #pragma unroll
      for (int df=0; df<4; ++df) {
        size_t voff = vbase + (size_t)(df*16 + (lane & 15))*SEQ + kt*128 + ks2*32 + (lane>>4)*8;
        f16x8 vb = *(const f16x8*)&Vt[voff];
        o[df] = __builtin_amdgcn_mfma_f32_16x16x32_f16(pa, vb, o[df],0,0,0);
      }
    }

    // write next K tile into the other buffer; single barrier per iteration
    if (kt < 15) {
      #pragma unroll
      for (int i=0;i<4;++i){
        int c = tid + i*256; int r = c>>3, sl = c&7;
        *(ushort8*)&Ks[cur^1][r*64 + ((sl^(r&7))*8)] = kreg[i];
      }
    }
    __syncthreads();
    cur ^= 1;
  }

  // write attention output (f16) back in [row][h*64+d] layout
  #pragma unroll
  for (int df=0; df<4; ++df)
    #pragma unroll
    for (int r=0;r<4;++r) {
      int prow = (lane>>4)*4 + r;
      int qrow = n*SEQ + qt*64 + w*16 + prow;
      int col  = h*64 + df*16 + (lane & 15);
      AO[(size_t)qrow*1024 + col] = f32_to_f16u(o[df][r] / lrun[r]);
    }
}

extern "C" void kernel_launch(void* const* d_in, const int* in_sizes, int n_in,
                              void* d_out, int out_size, void* d_ws, size_t ws_size,
                              hipStream_t stream)
{
  (void)in_sizes; (void)n_in; (void)out_size; (void)ws_size;
  const float* query = (const float*)d_in[0];
  const float* key   = (const float*)d_in[1];
  const float* value = (const float*)d_in[2];
  const float* Wq = (const float*)d_in[3];
  const float* bq = (const float*)d_in[4];
  const float* Wk = (const float*)d_in[5];
  const float* bk = (const float*)d_in[6];
  const float* Wv = (const float*)d_in[7];
  const float* bv = (const float*)d_in[8];
  const float* Wo = (const float*)d_in[9];
  const float* bo = (const float*)d_in[10];
  float* out = (float*)d_out;

  unsigned short* ws = (unsigned short*)d_ws;
  const size_t PLANE = (size_t)MROWS * 1024;
  unsigned short* Qf = ws;
  unsigned short* Kf = Qf + PLANE;
  unsigned short* Vt = Kf + PLANE;   // [ (n*16+h)*64+d ][ s ]
  unsigned short* AO = Vt + PLANE;

  dim3 bb(256);
  qkv_k <<<dim3(64,8,3), bb, 0, stream>>>(query,key,value, Wq,Wk,Wv, bq,bk,bv, Qf,Kf,Vt);
  attn_k<<<dim3(32,64), bb, 0, stream>>>(Qf, Kf, Vt, AO);
  oproj_k<<<dim3(64,8), bb, 0, stream>>>(AO, Wo, bo, out);
}

// Round 4
// 375.727 us; speedup vs baseline: 1.6698x; 1.4250x over previous
//
#include <hip/hip_runtime.h>
#include <stdint.h>

#define SEQ 2048
#define MROWS 8192
#define LOG2E 1.44269504f

typedef __attribute__((ext_vector_type(8))) _Float16 f16x8;
typedef __attribute__((ext_vector_type(2))) __fp16 fp16x2_t;   // cvt_pkrtz return type
typedef __attribute__((ext_vector_type(8))) unsigned short ushort8;
typedef __attribute__((ext_vector_type(4))) unsigned short ushort4_t;
typedef __attribute__((ext_vector_type(4))) float f32x4;

__device__ __forceinline__ unsigned short f32_to_f16u(float f) {
  union { _Float16 h; unsigned short u; } v; v.h = (_Float16)f; return v.u;
}

// ---------------- fused QKV projection GEMM ----------------
// z=0: Q -> f16 plane (pre-scaled by log2e); z=1: K -> f16 plane;
// z=2: V -> per-head transposed f16
__global__ __launch_bounds__(256) void qkv_k(
    const float* __restrict__ Aq, const float* __restrict__ Ak, const float* __restrict__ Av,
    const float* __restrict__ Wq, const float* __restrict__ Wk, const float* __restrict__ Wv,
    const float* __restrict__ bq, const float* __restrict__ bk, const float* __restrict__ bv,
    unsigned short* __restrict__ Qf, unsigned short* __restrict__ Kf, unsigned short* __restrict__ Vt)
{
  const int z = blockIdx.z;
  const float* __restrict__ A    = (z==0)? Aq : (z==1)? Ak : Av;
  const float* __restrict__ W    = (z==0)? Wq : (z==1)? Wk : Wv;
  const float* __restrict__ bias = (z==0)? bq : (z==1)? bk : bv;

  __shared__ unsigned short Ah[128*32];
  __shared__ unsigned short Bh[128*32];

  const int tid  = threadIdx.x;
  const int lane = tid & 63;
  const int w    = tid >> 6;
  const int wm   = w >> 1, wn = w & 1;
  const int row0 = blockIdx.x * 128;
  const int col0 = blockIdx.y * 128;

  f32x4 acc[4][4] = {};

  for (int k0 = 0; k0 < 1024; k0 += 32) {
    __syncthreads();
    #pragma unroll
    for (int i = 0; i < 2; ++i) {
      int c = tid + i*256;            // 0..511 chunks of 8 elements
      int r = c >> 2, slot = c & 3;   // 128 rows x 4 slots
      int lidx = r*32 + ((slot ^ ((r >> 1) & 3))*8);
      {
        const float* ap = A + (size_t)(row0 + r)*1024 + k0 + slot*8;
        float4 f0 = *(const float4*)ap;
        float4 f1 = *(const float4*)(ap + 4);
        float fs[8] = {f0.x,f0.y,f0.z,f0.w,f1.x,f1.y,f1.z,f1.w};
        ushort8 hv;
        #pragma unroll
        for (int j=0;j<8;++j) hv[j] = f32_to_f16u(fs[j]);
        *(ushort8*)&Ah[lidx] = hv;
      }
      {
        const float* bp = W + (size_t)(col0 + r)*1024 + k0 + slot*8;
        float4 f0 = *(const float4*)bp;
        float4 f1 = *(const float4*)(bp + 4);
        float fs[8] = {f0.x,f0.y,f0.z,f0.w,f1.x,f1.y,f1.z,f1.w};
        ushort8 hv;
        #pragma unroll
        for (int j=0;j<8;++j) hv[j] = f32_to_f16u(fs[j]);
        *(ushort8*)&Bh[lidx] = hv;
      }
    }
    __syncthreads();

    f16x8 a_[4], b_[4];
    const int slotR = lane >> 4;
    #pragma unroll
    for (int m=0;m<4;++m) {
      int r = wm*64 + m*16 + (lane & 15);
      a_[m] = *(const f16x8*)&Ah[r*32 + ((slotR ^ ((r>>1)&3))*8)];
    }
    #pragma unroll
    for (int nn=0;nn<4;++nn) {
      int r = wn*64 + nn*16 + (lane & 15);
      b_[nn] = *(const f16x8*)&Bh[r*32 + ((slotR ^ ((r>>1)&3))*8)];
    }
    #pragma unroll
    for (int m=0;m<4;++m)
      #pragma unroll
      for (int nn=0;nn<4;++nn)
        acc[m][nn] = __builtin_amdgcn_mfma_f32_16x16x32_f16(a_[m], b_[nn], acc[m][nn],0,0,0);
  }

  // epilogue (C frag: col=lane&15, row=(lane>>4)*4+r)
  #pragma unroll
  for (int m=0;m<4;++m) {
    #pragma unroll
    for (int nn=0;nn<4;++nn) {
      int gcol = col0 + wn*64 + nn*16 + (lane & 15);
      float bsv = bias[gcol];
      if (z == 2) {
        int rbase = row0 + wm*64 + m*16 + (lane>>4)*4;
        int nIdx = rbase >> 11, s0 = rbase & 2047;
        ushort4_t pk;
        #pragma unroll
        for (int r2=0;r2<4;++r2) pk[r2] = f32_to_f16u(acc[m][nn][r2] + bsv);
        *(ushort4_t*)&Vt[((size_t)(nIdx*1024 + gcol))*2048 + s0] = pk;
      } else {
        unsigned short* __restrict__ dst = (z==0)? Qf : Kf;
        const float qsc = (z==0)? LOG2E : 1.0f;   // fold log2(e) into Q
        #pragma unroll
        for (int r2=0;r2<4;++r2) {
          int grow = row0 + wm*64 + m*16 + (lane>>4)*4 + r2;
          dst[(size_t)grow*1024 + gcol] = f32_to_f16u((acc[m][nn][r2] + bsv) * qsc);
        }
      }
    }
  }
}

// ---------------- output projection: out = AO(f16) @ Wo^T + bo (f32) -------
__global__ __launch_bounds__(256) void oproj_k(
    const unsigned short* __restrict__ AO, const float* __restrict__ W,
    const float* __restrict__ bias, float* __restrict__ out)
{
  __shared__ unsigned short Ah[128*32];
  __shared__ unsigned short Bh[128*32];

  const int tid  = threadIdx.x;
  const int lane = tid & 63;
  const int w    = tid >> 6;
  const int wm   = w >> 1, wn = w & 1;
  const int row0 = blockIdx.x * 128;
  const int col0 = blockIdx.y * 128;

  f32x4 acc[4][4] = {};

  for (int k0 = 0; k0 < 1024; k0 += 32) {
    __syncthreads();
    #pragma unroll
    for (int i = 0; i < 2; ++i) {
      int c = tid + i*256;
      int r = c >> 2, slot = c & 3;
      int lidx = r*32 + ((slot ^ ((r >> 1) & 3))*8);
      *(ushort8*)&Ah[lidx] = *(const ushort8*)&AO[(size_t)(row0 + r)*1024 + k0 + slot*8];
      {
        const float* bp = W + (size_t)(col0 + r)*1024 + k0 + slot*8;
        float4 f0 = *(const float4*)bp;
        float4 f1 = *(const float4*)(bp + 4);
        float fs[8] = {f0.x,f0.y,f0.z,f0.w,f1.x,f1.y,f1.z,f1.w};
        ushort8 hv;
        #pragma unroll
        for (int j=0;j<8;++j) hv[j] = f32_to_f16u(fs[j]);
        *(ushort8*)&Bh[lidx] = hv;
      }
    }
    __syncthreads();

    f16x8 a_[4], b_[4];
    const int slotR = lane >> 4;
    #pragma unroll
    for (int m=0;m<4;++m) {
      int r = wm*64 + m*16 + (lane & 15);
      a_[m] = *(const f16x8*)&Ah[r*32 + ((slotR ^ ((r>>1)&3))*8)];
    }
    #pragma unroll
    for (int nn=0;nn<4;++nn) {
      int r = wn*64 + nn*16 + (lane & 15);
      b_[nn] = *(const f16x8*)&Bh[r*32 + ((slotR ^ ((r>>1)&3))*8)];
    }
    #pragma unroll
    for (int m=0;m<4;++m)
      #pragma unroll
      for (int nn=0;nn<4;++nn)
        acc[m][nn] = __builtin_amdgcn_mfma_f32_16x16x32_f16(a_[m], b_[nn], acc[m][nn],0,0,0);
  }

  #pragma unroll
  for (int m=0;m<4;++m)
    #pragma unroll
    for (int nn=0;nn<4;++nn) {
      int gcol = col0 + wn*64 + nn*16 + (lane & 15);
      float bsv = bias[gcol];
      #pragma unroll
      for (int r2=0;r2<4;++r2) {
        int grow = row0 + wm*64 + m*16 + (lane>>4)*4 + r2;
        out[(size_t)grow*1024 + gcol] = acc[m][nn][r2] + bsv;
      }
    }
}

// ---------------- Flash attention, swapped-operand (T12-style) -------------
// grid (32 qtiles, 64 n*h); 4 waves x 16 q-rows; KVBLK=64.
// QK^T computed as mfma(K,Q) -> S^T: lane owns row q=lane&15, k=nf*16+4g+r.
// Softmax: lane-local over 16 + 2 shfl_xor. PV as mfma(V^T,P) -> O^T: col=q,
// so rescale/normalize are scalar per lane.
__global__ __launch_bounds__(256) void attn_k(
  const unsigned short* __restrict__ Qf, const unsigned short* __restrict__ Kf,
  const unsigned short* __restrict__ Vt, unsigned short* __restrict__ AO)
{
  __shared__ unsigned short Ks[2][64*64];   // double-buffered K tile (swizzled)
  __shared__ unsigned short Ps[4][16*64];   // per-wave P (16 q x 64 k, swizzled)

  const int tid = threadIdx.x, lane = tid & 63, w = tid >> 6;
  const int q = lane & 15, g = lane >> 4;
  const int qt = blockIdx.x, nh = blockIdx.y;
  const int n = nh >> 4, h = nh & 15;

  // Q fragment (pre-scaled by log2e): q-row = base + (lane&15)
  f16x8 qf[2];
  {
    int qrow = n*SEQ + qt*64 + w*16 + q;
    #pragma unroll
    for (int ks=0; ks<2; ++ks)
      qf[ks] = *(const f16x8*)&Qf[(size_t)qrow*1024 + h*64 + ks*32 + g*8];
  }

  f32x4 o[4] = {};          // O^T frag: o[df][r] = O[q][d=df*16+4g+r]
  float mrun = -1e30f, lrun = 0.f;

  const size_t kbase = (size_t)(n*SEQ)*1024 + h*64;
  const size_t vbase = ((size_t)(n*1024 + h*64))*SEQ;

  // prologue: stage K tile 0 (64 rows x 64 d, 8-slot XOR swizzle)
  ushort8 kreg[2];
  #pragma unroll
  for (int i=0;i<2;++i){
    int c = tid + i*256; int r = c>>3, sl = c&7;
    kreg[i] = *(const ushort8*)&Kf[kbase + (size_t)r*1024 + sl*8];
  }
  #pragma unroll
  for (int i=0;i<2;++i){
    int c = tid + i*256; int r = c>>3, sl = c&7;
    *(ushort8*)&Ks[0][r*64 + ((sl^(r&7))*8)] = kreg[i];
  }
  __syncthreads();

  int cur = 0;
  for (int kt = 0; kt < 32; ++kt) {
    // prefetch next K tile to regs (latency hides under compute)
    if (kt < 31) {
      #pragma unroll
      for (int i=0;i<2;++i){
        int c = tid + i*256; int r = c>>3, sl = c&7;
        kreg[i] = *(const ushort8*)&Kf[kbase + (size_t)((kt+1)*64 + r)*1024 + sl*8];
      }
    }

    // S^T = K * Q^T : s[nf][r] = S[q][k = nf*16 + 4g + r]
    f32x4 s[4];
    #pragma unroll
    for (int nf=0; nf<4; ++nf) s[nf] = f32x4{0.f,0.f,0.f,0.f};
    #pragma unroll
    for (int nf=0; nf<4; ++nf) {
      int rr = nf*16 + q;
      #pragma unroll
      for (int ks=0; ks<2; ++ks) {
        int sl = ks*4 + g;
        f16x8 kb = *(const f16x8*)&Ks[cur][rr*64 + ((sl^(rr&7))*8)];
        s[nf] = __builtin_amdgcn_mfma_f32_16x16x32_f16(kb, qf[ks], s[nf],0,0,0);
      }
    }

    // online softmax: lane-local (16 vals) + 2 shuffle steps across g-group
    float tm = s[0][0];
    #pragma unroll
    for (int nf=0; nf<4; ++nf)
      #pragma unroll
      for (int r=0;r<4;++r) tm = fmaxf(tm, s[nf][r]);
    tm = fmaxf(tm, __shfl_xor(tm, 16, 64));
    tm = fmaxf(tm, __shfl_xor(tm, 32, 64));
    float mn = fmaxf(mrun, tm);
    float sc = __builtin_amdgcn_exp2f(mrun - mn);   // S already in log2 domain
    float pv[16];
    float rs = 0.f;
    #pragma unroll
    for (int nf=0; nf<4; ++nf)
      #pragma unroll
      for (int r=0;r<4;++r) {
        float p = __builtin_amdgcn_exp2f(s[nf][r] - mn);
        pv[nf*4+r] = p; rs += p;
      }
    rs += __shfl_xor(rs, 16, 64);
    rs += __shfl_xor(rs, 32, 64);
    lrun = lrun*sc + rs;
    mrun = mn;
    #pragma unroll
    for (int df=0; df<4; ++df)
      #pragma unroll
      for (int r=0;r<4;++r) o[df][r] *= sc;

    // pack P (f16) and write to per-wave LDS: row q, k0 = nf*16 + 4g (8B)
    #pragma unroll
    for (int nf=0; nf<4; ++nf) {
      union { fp16x2_t h2[2]; ushort4_t u4; } pk;
      pk.h2[0] = __builtin_amdgcn_cvt_pkrtz(pv[nf*4+0], pv[nf*4+1]);
      pk.h2[1] = __builtin_amdgcn_cvt_pkrtz(pv[nf*4+2], pv[nf*4+3]);
      int gi = 2*nf + (g>>1);                       // 16B granule index
      int idx = q*64 + ((gi ^ (q&7))*8) + (g&1)*4;  // ushort units
      *(ushort4_t*)&Ps[w][idx] = pk.u4;
    }

    // O^T += V^T * P : pa frag has n=q, kk = 32*s2 + 8g + j (16B read)
    #pragma unroll
    for (int s2=0; s2<2; ++s2) {
      f16x8 pa = *(const f16x8*)&Ps[w][q*64 + (((4*s2+g) ^ (q&7))*8)];
      #pragma unroll
      for (int df=0; df<4; ++df) {
        size_t voff = vbase + (size_t)(df*16 + q)*SEQ + kt*64 + s2*32 + g*8;
        f16x8 vb = *(const f16x8*)&Vt[voff];
        o[df] = __builtin_amdgcn_mfma_f32_16x16x32_f16(vb, pa, o[df],0,0,0);
      }
    }

    // write next K tile into the other buffer; single barrier per iteration
    if (kt < 31) {
      #pragma unroll
      for (int i=0;i<2;++i){
        int c = tid + i*256; int r = c>>3, sl = c&7;
        *(ushort8*)&Ks[cur^1][r*64 + ((sl^(r&7))*8)] = kreg[i];
      }
    }
    __syncthreads();
    cur ^= 1;
  }

  // epilogue: AO[qrow][h*64 + df*16 + 4g + r] = O/lsum
  float inv = 1.0f / lrun;
  int qrow = n*SEQ + qt*64 + w*16 + q;
  #pragma unroll
  for (int df=0; df<4; ++df)
    #pragma unroll
    for (int r=0;r<4;++r)
      AO[(size_t)qrow*1024 + h*64 + df*16 + g*4 + r] = f32_to_f16u(o[df][r] * inv);
}

extern "C" void kernel_launch(void* const* d_in, const int* in_sizes, int n_in,
                              void* d_out, int out_size, void* d_ws, size_t ws_size,
                              hipStream_t stream)
{
  (void)in_sizes; (void)n_in; (void)out_size; (void)ws_size;
  const float* query = (const float*)d_in[0];
  const float* key   = (const float*)d_in[1];
  const float* value = (const float*)d_in[2];
  const float* Wq = (const float*)d_in[3];
  const float* bq = (const float*)d_in[4];
  const float* Wk = (const float*)d_in[5];
  const float* bk = (const float*)d_in[6];
  const float* Wv = (const float*)d_in[7];
  const float* bv = (const float*)d_in[8];
  const float* Wo = (const float*)d_in[9];
  const float* bo = (const float*)d_in[10];
  float* out = (float*)d_out;

  unsigned short* ws = (unsigned short*)d_ws;
  const size_t PLANE = (size_t)MROWS * 1024;
  unsigned short* Qf = ws;
  unsigned short* Kf = Qf + PLANE;
  unsigned short* Vt = Kf + PLANE;   // [ (n*16+h)*64+d ][ s ]
  unsigned short* AO = Vt + PLANE;

  dim3 bb(256);
  qkv_k <<<dim3(64,8,3), bb, 0, stream>>>(query,key,value, Wq,Wk,Wv, bq,bk,bv, Qf,Kf,Vt);
  attn_k<<<dim3(32,64), bb, 0, stream>>>(Qf, Kf, Vt, AO);
  oproj_k<<<dim3(64,8), bb, 0, stream>>>(AO, Wo, bo, out);
}